// Round 2
// baseline (135.943 us; speedup 1.0000x reference)
//
#include <hip/hip_runtime.h>
#include <math.h>

// Problem constants
constexpr int Bn = 32;
constexpr int Cn = 512;
constexpr int Tn = 1024;
constexpr int KS = 13;

// Tiling
constexpr int CB   = 16;           // channels per block -> 1024 blocks, 4 blocks/CU
constexpr int TT   = 64;           // timesteps per chunk
constexpr int NCH  = Tn / TT;      // 16 chunks
constexpr int DSTR = 68;           // D row stride (floats): 272B = 16B-aligned, 2-way banks (free)
constexpr int NCW  = 4;            // conv waves
constexpr int SEG  = CB / NCW;     // 4 output rows per conv thread
constexpr int NW   = SEG + KS - 1; // 16 window rows per conv thread (from LDS)
constexpr int XR   = CB + KS - 1;  // 28 staged x rows per chunk
constexpr int RPW  = XR / NCW;     // 7 rows staged per conv wave

// ---------------------------------------------------------------------------
// r10: r9's counters (Occ 23%, VALU 37%, HBM 32%, nothing saturated) say the
// duration = fixed VALU work / VALUBusy, and VALUBusy is capped by 2 blocks/CU
// (grid=512 was the limiter, not LDS/VGPR). Fixes:
//  (1) CB 32->16: 1024 blocks -> 4 blocks/CU (24 waves/CU). LDS ~30KB/block,
//      __launch_bounds__(384,6) keeps VGPR<=85 for 6 waves/SIMD.
//  (2) x-tile LDS staging via global_load_lds (7 rows/wave/chunk, counted
//      vmcnt(7), distance-2 ring over three NAMED arrays XA/XB/XC so alias
//      analysis can prove staged-buffer != read-buffer and never inserts a
//      vmcnt(0) drain). Kills the CB-shrink halo blowup (2.5x -> 1.75x read
//      demand) and deletes the 60-float register ring (VGPR headroom).
//  (3) scan reads D via ds_read_b128 (4x fewer LDS instrs; stride 68 rows are
//      16B-aligned, 2-way bank aliasing only = free).
// Barrier schedule: 18 barriers per role (B0..B17), double-buffered D/Sb,
// triple-ring X. Edge channels: clamped staging + reader-side register
// masking (keeps staging count uniform => vmcnt(7) exact).
// Math (kw double-exp emulation, ascending no-FMA conv, SCAN16, store) is
// bit-identical to the validated r2..r9 kernels.
// ---------------------------------------------------------------------------

__device__ __forceinline__ void wg_barrier() {
  asm volatile("" ::: "memory");
  __builtin_amdgcn_s_barrier();
  asm volatile("" ::: "memory");
}
__device__ __forceinline__ void lds_fence() {
  asm volatile("s_waitcnt lgkmcnt(0)" ::: "memory");
}
#define VMCNT_(n) asm volatile("s_waitcnt vmcnt(" #n ")" ::: "memory")
#define VMCNT(n) VMCNT_(n)

// async global->LDS, 4B per lane, dest = uniform base + lane*4
__device__ __forceinline__ void gload4(const float* g, float* l) {
  __builtin_amdgcn_global_load_lds(
      (const __attribute__((address_space(1))) unsigned int*)g,
      (__attribute__((address_space(3))) unsigned int*)l, 4, 0, 0);
}

#define SCAN16(DV, TB)                                                   \
  _Pragma("unroll")                                                      \
  for (int j = 0; j < 16; ++j) {                                         \
    const float rthr = (mem > 0.5f) ? 0.5f : 0.0f;  /* reset: OLD mem */ \
    float a_  = __fmul_rn(0.95f, mem);                                   \
    float s2_ = __fadd_rn(a_, DV[j]);                                    \
    mem = __fsub_rn(s2_, rthr);                                          \
    const unsigned int bit = (mem > 0.5f) ? 1u : 0u;                     \
    if ((TB) + j < 32) lo |= bit << ((TB) + j);                          \
    else               hi |= bit << ((TB) + j - 32);                     \
  }

// unpack one group of 4 float4s from Dv into a 16-float register array
#define LOADG(DV, G)                                                     \
  { float4 t0_ = Dv[4*(G)+0], t1_ = Dv[4*(G)+1],                         \
           t2_ = Dv[4*(G)+2], t3_ = Dv[4*(G)+3];                         \
    DV[0]=t0_.x;  DV[1]=t0_.y;  DV[2]=t0_.z;  DV[3]=t0_.w;               \
    DV[4]=t1_.x;  DV[5]=t1_.y;  DV[6]=t1_.z;  DV[7]=t1_.w;               \
    DV[8]=t2_.x;  DV[9]=t2_.y;  DV[10]=t2_.z; DV[11]=t2_.w;              \
    DV[12]=t3_.x; DV[13]=t3_.y; DV[14]=t3_.z; DV[15]=t3_.w; }

__global__ __launch_bounds__(384, 6)
void snn_fused(const float* __restrict__ x, const float* __restrict__ wp,
               float* __restrict__ out) {
  // x-tile ring (3 named arrays: provable no-alias between stage and read)
  __shared__ __align__(16) float XA[XR][TT];   // 7  KB each
  __shared__ __align__(16) float XB[XR][TT];
  __shared__ __align__(16) float XC[XR][TT];
  __shared__ __align__(16) float DA[CB][DSTR]; // drive double buffer
  __shared__ __align__(16) float DB[CB][DSTR];
  __shared__ unsigned long long SbA[CB], SbB[CB]; // spike bitmask dbuf

  const int tid = threadIdx.x;
  const int b   = blockIdx.y;
  const int c0  = blockIdx.x * CB;
  const long xbase = (long)b * Cn * Tn;

  if (tid < 64) {
    // ======================= scan wave (lanes >= CB masked) =============
    const int c = tid;
    float mem = 0.0f;
    wg_barrier();                              // B0
    wg_barrier();                              // B1 (D(0) published)
    for (int k = 0; k < NCH; ++k) {
      if (c < CB) {
        const float4* Dv =
            (const float4*)((k & 1) ? &DB[c][0] : &DA[c][0]);
        unsigned int lo = 0u, hi = 0u;
        float dvA[16], dvB[16];                // named arrays, const idx only
        LOADG(dvA, 0)
        LOADG(dvB, 1)                          // lookahead g=1
        SCAN16(dvA, 0)
        LOADG(dvA, 2)                          // lookahead g=2
        SCAN16(dvB, 16)
        LOADG(dvB, 3)                          // lookahead g=3
        SCAN16(dvA, 32)
        SCAN16(dvB, 48)
        ((k & 1) ? SbB : SbA)[c] =
            ((unsigned long long)hi << 32) | (unsigned long long)lo;
      }
      lds_fence();                             // Sb write retired pre-barrier
      wg_barrier();                            // B(k+2)
    }
  } else if (tid < 64 + 64 * NCW) {
    // ============== conv waves: stage x-tile + conv from LDS ============
    const int ctid = tid - 64;
    const int col  = ctid & 63;                // t-column (lane)
    const int wid  = ctid >> 6;                // 0..3
    const int segS = wid * SEG;                // 0,4,8,12
    const int rw0  = wid * RPW;                // staged rows rw0..rw0+6

    // ---- Gaussian weights, numpy float32 bit-emulation (validated) ----
    float kw[KS];
    {
      float w  = wp[0];
      float wc = fminf(fmaxf(w, 1.0f), 10.0f);     // clip(w, 1, 10)
      float sigma = __fadd_rn(5.5f, wc);
      float e[KS];
#pragma unroll
      for (int i = 0; i < KS; ++i) {
        float q = __fdiv_rn((float)(i - 6), sigma);
        float t = __fmul_rn(-0.5f, __fmul_rn(q, q));
        e[i] = (float)exp((double)t);
      }
      // numpy pairwise_sum order for n=13
      float s = __fadd_rn(
          __fadd_rn(__fadd_rn(e[0], e[1]), __fadd_rn(e[2], e[3])),
          __fadd_rn(__fadd_rn(e[4], e[5]), __fadd_rn(e[6], e[7])));
      s = __fadd_rn(s, e[8]);  s = __fadd_rn(s, e[9]);  s = __fadd_rn(s, e[10]);
      s = __fadd_rn(s, e[11]); s = __fadd_rn(s, e[12]);
#pragma unroll
      for (int i = 0; i < KS; ++i) kw[i] = __fdiv_rn(e[i], s);
    }

    // clamped per-row source offsets (uniform -> SGPRs) + lane col
    long rowoff[RPW];
#pragma unroll
    for (int q = 0; q < RPW; ++q) {
      int gc = c0 - 6 + rw0 + q;
      gc = gc < 0 ? 0 : (gc >= Cn ? Cn - 1 : gc);  // clamp (reader masks)
      rowoff[q] = xbase + (long)gc * Tn;
    }

    auto stage = [&](int m, float (*X)[TT]) {    // 7 x global_load_lds
#pragma unroll
      for (int q = 0; q < RPW; ++q)
        gload4(x + rowoff[q] + m * TT + col, &X[rw0 + q][0]);
    };

    // reader-side validity (uniform per wave)
    const int  cw0  = c0 - 6 + segS;             // gc of window row 0
    const bool edge = (cw0 < 0) || (cw0 + NW > Cn);

    auto convc = [&](const float (*X)[TT], float (*D)[DSTR]) {
      float w[NW];
#pragma unroll
      for (int i = 0; i < NW; ++i) w[i] = X[segS + i][col];
      if (edge) {
#pragma unroll
        for (int i = 0; i < NW; ++i)
          if (cw0 + i < 0 || cw0 + i >= Cn) w[i] = 0.0f;  // zero pad
      }
#pragma unroll
      for (int r = 0; r < SEG; ++r) {
        float acc = __fmul_rn(kw[0], w[r]);      // ascending, no FMA
#pragma unroll
        for (int i = 1; i < KS; ++i)
          acc = __fadd_rn(acc, __fmul_rn(kw[i], w[r + i]));
        D[segS + r][col] = __fsub_rn(w[r + 6], acc);      // x - x_mean
      }
    };

    // prologue: fill ring, publish D(0)
    stage(0, XA);
    stage(1, XB);
    stage(2, XC);
    VMCNT(14);                                  // chunk 0 landed
    wg_barrier();                               // B0
    convc(XA, DA);                              // chunk 0 -> DA
    VMCNT(7);                                   // chunk 1 landed
    lds_fence();
    wg_barrier();                               // B1

    // STEP(K): stage chunk K+3 -> X[K%3], conv chunk K+1 from X[(K+1)%3]
    // into D[(K+1)&1]; counted vmcnt (7 while staging, 0 in tail) ensures
    // chunk K+2 is resident before the barrier that publishes it.
#define STEPX(K, XST, XRD, DD, N)                                        \
    do {                                                                 \
      if ((K) + 3 < NCH) stage((K) + 3, XST);                            \
      convc(XRD, DD);                                                    \
      VMCNT(N);                                                          \
      lds_fence();                                                       \
      wg_barrier();                                                      \
    } while (0)

    STEPX(0,  XA, XB, DB, 7);
    STEPX(1,  XB, XC, DA, 7);
    STEPX(2,  XC, XA, DB, 7);
    STEPX(3,  XA, XB, DA, 7);
    STEPX(4,  XB, XC, DB, 7);
    STEPX(5,  XC, XA, DA, 7);
    STEPX(6,  XA, XB, DB, 7);
    STEPX(7,  XB, XC, DA, 7);
    STEPX(8,  XC, XA, DB, 7);
    STEPX(9,  XA, XB, DA, 7);
    STEPX(10, XB, XC, DB, 7);
    STEPX(11, XC, XA, DA, 7);
    STEPX(12, XA, XB, DB, 7);
    STEPX(13, XB, XC, DA, 0);                   // no stage; drain chunk 15
    STEPX(14, XC, XA, DB, 0);                   // no stage
#undef STEPX
    wg_barrier();                               // B17 (idle, match count)
  } else {
    // ====== store wave (LDS reads + global stores, NEVER waits vmcnt) ===
    const int col = tid & 63;                   // t-column (lane)
    wg_barrier();                               // B0
    wg_barrier();                               // B1
    for (int k = 0; k < NCH; ++k) {
      wg_barrier();                             // B(k+2): Sb(k) published
      const unsigned long long* Sp = (k & 1) ? SbB : SbA;
      const long obase = xbase + (long)c0 * Tn + (long)k * TT + col;
#pragma unroll
      for (int r = 0; r < CB; ++r) {
        const unsigned long long wb = Sp[r];               // LDS broadcast
        const float v = ((wb >> col) & 1ull) ? 1.0f : 0.0f;
        out[obase + (long)r * Tn] = v;                     // fire & forget
      }
    }
  }
}

extern "C" void kernel_launch(void* const* d_in, const int* in_sizes, int n_in,
                              void* d_out, int out_size, void* d_ws, size_t ws_size,
                              hipStream_t stream) {
  const float* x  = (const float*)d_in[0];
  const float* w  = (const float*)d_in[1];
  float* out      = (float*)d_out;
  dim3 grid(Cn / CB, Bn, 1);
  snn_fused<<<grid, 384, 0, stream>>>(x, w, out);
}